// Round 1
// 172.730 us; speedup vs baseline: 1.0018x; 1.0018x over previous
//
#include <hip/hip_runtime.h>
#include <hip/hip_bf16.h>

#define LEN 128
#define NB 32
#define NC 16
#define NU 16
#define NK 5
#define KC 80          // (k,c) pairs
#define KCP 96         // padded K for stage2
#define LUN 80         // (l,u) pairs

typedef unsigned int uint32;
typedef unsigned short ushort16;
typedef __attribute__((ext_vector_type(8))) short bf16x8;
typedef __attribute__((ext_vector_type(4))) float f32x4;

#define MFMA(a, b, c) __builtin_amdgcn_mfma_f32_16x16x32_bf16(a, b, c, 0, 0, 0)

// XOR swizzle of the 16B-unit index within a 64-dword (16-unit) row.
// Mixes row bits 0..3 with bits 3..6 so BOTH write lanes (row stride 8)
// and read lanes (row stride 1) spread across banks. Bijective per row.
#define SIG(r) (((r) & 15) ^ (((r) >> 3) & 15))

static __device__ inline ushort16 f2bf(float f) {
    union { float f; uint32 u; } v; v.f = f;
    uint32 u = v.u;
    uint32 r = (u + 0x7fffu + ((u >> 16) & 1u)) >> 16;   // RNE
    return (ushort16)r;
}
static __device__ inline uint32 pkbf(float a, float b) {   // low=a, high=b
    return (uint32)f2bf(a) | ((uint32)f2bf(b) << 16);
}
static __device__ inline bf16x8 frag16(const void* p) {    // 16B-aligned
    return *(const bf16x8*)p;
}

// ---------------- k0: precompute bf16 operand layouts ----------------
// cheb1T[kp=k*128+p][h]  (640x128)   = cheb1[k][h][p]
// cheb2T[q][l*128+w]     (128x640)   = cheb2[l][w][q]
// coefTT[lu=l*16+u][kc]  (80x96, kc>=80 zero) = coefs[k][l][c][u]
__global__ __launch_bounds__(256) void k0_prep(const float* __restrict__ coefs,
                                               const float* __restrict__ cheb1,
                                               const float* __restrict__ cheb2,
                                               ushort16* __restrict__ cheb1T,
                                               ushort16* __restrict__ cheb2T,
                                               ushort16* __restrict__ coefTT) {
    int i = blockIdx.x * 256 + threadIdx.x;
    if (i < 81920) {
        int kp = i >> 7, h = i & 127;
        int k = kp >> 7, p = kp & 127;
        cheb1T[i] = f2bf(cheb1[(k * LEN + h) * LEN + p]);
    } else if (i < 163840) {
        int j = i - 81920;
        int q = j / 640, t = j % 640;
        int l = t >> 7, w = t & 127;
        cheb2T[j] = f2bf(cheb2[(l * LEN + w) * LEN + q]);
    } else if (i < 171520) {
        int j = i - 163840;
        int lu = j / KCP, kc = j % KCP;
        int l = lu >> 4, u = lu & 15, k = kc >> 4, c = kc & 15;
        coefTT[j] = (kc < KC) ? f2bf(coefs[((k * NK + l) * NC + c) * NU + u]) : (ushort16)0;
    }
}

// ---------------- k1: t1[bl][p][k][c][w] = sum_h cheb1[k][h][p]*x[b][c][h][w]
// per (c,bl) block. GEMM M=128 (w), N=640 (kp, 4 passes of 160), K=128 (h).
// Wave tile: 64 w (4 m-tiles) x 80 kp (5 n-tiles), waves 2x2.
// LDS rows are 64 dw with XOR-swizzled 16B units (see SIG).
__global__ __launch_bounds__(256, 2) void k1_mfma(const float* __restrict__ x,
                                                  const uint32* __restrict__ cheb1T,  // dword view, 64 dw/row
                                                  ushort16* __restrict__ t1, int b0) {
    __shared__ __align__(16) uint32 Xs[128 * 64];  // A: [w][h-pair units swizzled]
    __shared__ __align__(16) uint32 As[160 * 64];  // B: [kp][h-pair units swizzled]
    const int c = blockIdx.x, bl = blockIdx.y, b = b0 + bl;
    const int tid = threadIdx.x;
    const int lane = tid & 63, wave = tid >> 6;
    const int m16 = lane & 15, g = lane >> 4;
    const int wm = wave >> 1, wn = wave & 1;

    // stage Xs (transpose + cvt), coalesced along w; b128 swizzled writes
    {
        const float* xp = x + (size_t)(b * NC + c) * (LEN * LEN);
        int w = tid & 127, hg = tid >> 7;
        #pragma unroll
        for (int uu = 0; uu < 8; ++uu) {
            int u = hg * 8 + uu;
            uint4 d;
            uint32* dp = (uint32*)&d;
            #pragma unroll
            for (int t = 0; t < 4; ++t) {
                int h2 = u * 4 + t;
                dp[t] = pkbf(xp[(2 * h2) * LEN + w], xp[(2 * h2 + 1) * LEN + w]);
            }
            *(uint4*)(Xs + w * 64 + ((u ^ SIG(w)) << 2)) = d;
        }
    }

    for (int pass = 0; pass < 4; ++pass) {
        __syncthreads();   // prev As readers done (pass0: also orders Xs writes)
        #pragma unroll
        for (int i = 0; i < 10; ++i) {
            int it = tid + i * 256;          // 0..2559
            int r = it >> 4, cc = it & 15;
            uint4 v = *(const uint4*)(cheb1T + (size_t)(pass * 160 + r) * 64 + cc * 4);
            *(uint4*)(As + r * 64 + ((cc ^ SIG(r)) << 2)) = v;
        }
        __syncthreads();

        f32x4 acc[4][5];
        #pragma unroll
        for (int mi = 0; mi < 4; ++mi)
            #pragma unroll
            for (int ni = 0; ni < 5; ++ni) acc[mi][ni] = (f32x4)0.f;

        #pragma unroll
        for (int ks = 0; ks < 4; ++ks) {
            bf16x8 Af[4], Bf[5];
            #pragma unroll
            for (int mi = 0; mi < 4; ++mi) {
                int row = wm * 64 + mi * 16 + m16;
                Af[mi] = frag16(Xs + row * 64 + (((ks * 4 + g) ^ SIG(row)) << 2));
            }
            #pragma unroll
            for (int ni = 0; ni < 5; ++ni) {
                int row = wn * 80 + ni * 16 + m16;
                Bf[ni] = frag16(As + row * 64 + (((ks * 4 + g) ^ SIG(row)) << 2));
            }
            #pragma unroll
            for (int mi = 0; mi < 4; ++mi)
                #pragma unroll
                for (int ni = 0; ni < 5; ++ni)
                    acc[mi][ni] = MFMA(Af[mi], Bf[ni], acc[mi][ni]);
        }

        // epilogue: lane holds 4 consecutive w at fixed kp -> dwordx2 stores
        #pragma unroll
        for (int ni = 0; ni < 5; ++ni) {
            int kp = pass * 160 + wn * 80 + ni * 16 + m16;
            int k = kp >> 7, p = kp & 127;
            size_t base = (((size_t)(bl * LEN + p) * NK + k) * NC + c) * LEN;
            #pragma unroll
            for (int mi = 0; mi < 4; ++mi) {
                int w0 = wm * 64 + mi * 16 + g * 4;
                uint2 d;
                d.x = pkbf(acc[mi][ni][0], acc[mi][ni][1]);
                d.y = pkbf(acc[mi][ni][2], acc[mi][ni][3]);
                *(uint2*)((ushort16*)t1 + base + w0) = d;
            }
        }
    }
}

// ---------------- k2: per (pg, bl) block, 2 p-slices (p = 2pg, 2pg+1)
// stage2: s[w(256)][lu(80)] = Ts[w][kc] x coefTT[lu][kc], K=96
// stage3: out[pu(32)][q(128)] = A3[pu][lw] x cheb2T[q][lw], K=640
// Ts rows are 64 dw with XOR-swizzled 16B units (conflict-free transpose).
__global__ __launch_bounds__(256, 2) void k2_mfma(const ushort16* __restrict__ t1,
                                                  const ushort16* __restrict__ coefTT,
                                                  const ushort16* __restrict__ cheb2T,
                                                  float* __restrict__ out, int b0) {
    __shared__ __align__(16) uint32 sm[2 * 128 * 64];   // Ts [row(256)][16 units swz]; A3 aliases
    const int pg = blockIdx.x, bl = blockIdx.y, b = b0 + bl;
    const int tid = threadIdx.x;
    const int lane = tid & 63, wave = tid >> 6;
    const int n16 = lane & 15, g = lane >> 4;

    // stage t1 (2 contiguous 20KB slices) -> Ts[row][kc] (kc-pairs packed in dwords)
    {
        const uint32* t1u = (const uint32*)(t1 + (size_t)(bl * LEN + 2 * pg) * (KC * LEN));
        #pragma unroll
        for (int i = 0; i < 5; ++i) {
            int it = tid + i * 256;          // 0..1279
            int p_i = (it >= 640) ? 1 : 0;
            int rem = it - 640 * p_i;
            int kc2 = rem >> 4, wq = rem & 15;
            const uint32* src = t1u + p_i * 5120 + kc2 * 128 + wq * 4;
            uint4 Av = *(const uint4*)(src);
            uint4 Bv = *(const uint4*)(src + 64);
            const uint32* av = (const uint32*)&Av;
            const uint32* bv = (const uint32*)&Bv;
            int u = kc2 >> 2, lo = kc2 & 3;
            #pragma unroll
            for (int j = 0; j < 4; ++j) {
                int r0 = p_i * 128 + wq * 8 + 2 * j;
                int r1 = r0 + 1;
                sm[r0 * 64 + ((u ^ SIG(r0)) << 2) + lo] = (av[j] & 0xffffu) | (bv[j] << 16);
                sm[r1 * 64 + ((u ^ SIG(r1)) << 2) + lo] = (av[j] >> 16) | (bv[j] & 0xffff0000u);
            }
        }
        for (int j = tid; j < 2048; j += 256) {   // zero K-pad (dword cols 40..47 = units 10,11)
            int row = j >> 3, d = j & 7;
            int u = 10 + (d >> 2);
            sm[row * 64 + ((u ^ SIG(row)) << 2) + (d & 3)] = 0;
        }
    }
    __syncthreads();

    // ---- stage2: wave = (wp = wave>>1 -> p, ww = wave&1 -> w-half)
    const int wp = wave >> 1, ww = wave & 1;
    f32x4 acc[4][5];
    #pragma unroll
    for (int mi = 0; mi < 4; ++mi)
        #pragma unroll
        for (int ni = 0; ni < 5; ++ni) acc[mi][ni] = (f32x4)0.f;

    #pragma unroll
    for (int ks = 0; ks < 3; ++ks) {
        bf16x8 Af[4], Bf[5];
        #pragma unroll
        for (int mi = 0; mi < 4; ++mi) {
            int row = wp * 128 + ww * 64 + mi * 16 + n16;
            Af[mi] = frag16(sm + row * 64 + (((ks * 4 + g) ^ SIG(row)) << 2));
        }
        #pragma unroll
        for (int ni = 0; ni < 5; ++ni)
            Bf[ni] = frag16(coefTT + (size_t)(ni * 16 + n16) * KCP + ks * 32 + g * 8);
        #pragma unroll
        for (int mi = 0; mi < 4; ++mi)
            #pragma unroll
            for (int ni = 0; ni < 5; ++ni)
                acc[mi][ni] = MFMA(Af[mi], Bf[ni], acc[mi][ni]);
    }
    __syncthreads();   // all Ts reads done; A3 may overwrite

    // s -> A3 bf16 A-layout: row pu = p_local*16+u (stride 648 bf16), col l*128+w
    {
        ushort16* A3 = (ushort16*)sm;
        #pragma unroll
        for (int mi = 0; mi < 4; ++mi)
            #pragma unroll
            for (int ni = 0; ni < 5; ++ni) {
                int lu = ni * 16 + n16, u = lu & 15, l = lu >> 4;
                int w0 = ww * 64 + mi * 16 + g * 4;
                int pu = wp * 16 + u;
                uint2 d;
                d.x = pkbf(acc[mi][ni][0], acc[mi][ni][1]);
                d.y = pkbf(acc[mi][ni][2], acc[mi][ni][3]);
                *(uint2*)(A3 + pu * 648 + l * 128 + w0) = d;
            }
    }
    __syncthreads();

    // ---- stage3: M=32 (pu), wave owns 32 q
    const ushort16* A3r = (const ushort16*)sm;
    f32x4 c3[2][2];
    c3[0][0] = (f32x4)0.f; c3[0][1] = (f32x4)0.f;
    c3[1][0] = (f32x4)0.f; c3[1][1] = (f32x4)0.f;
    #pragma unroll 5
    for (int ks = 0; ks < 20; ++ks) {
        bf16x8 Af2[2], Bf2[2];
        #pragma unroll
        for (int mi = 0; mi < 2; ++mi)
            Af2[mi] = frag16(A3r + (mi * 16 + n16) * 648 + ks * 32 + g * 8);
        #pragma unroll
        for (int nt = 0; nt < 2; ++nt)
            Bf2[nt] = frag16(cheb2T + (size_t)(wave * 32 + nt * 16 + n16) * 640 + ks * 32 + g * 8);
        #pragma unroll
        for (int mi = 0; mi < 2; ++mi)
            #pragma unroll
            for (int nt = 0; nt < 2; ++nt)
                c3[mi][nt] = MFMA(Af2[mi], Bf2[nt], c3[mi][nt]);
    }

    #pragma unroll
    for (int mi = 0; mi < 2; ++mi)
        #pragma unroll
        for (int nt = 0; nt < 2; ++nt)
            #pragma unroll
            for (int r = 0; r < 4; ++r) {
                int u = g * 4 + r;
                int q = wave * 32 + nt * 16 + n16;
                out[(((size_t)(b * NU + u)) * LEN + (2 * pg + mi)) * LEN + q] = c3[mi][nt][r];
            }
}

extern "C" void kernel_launch(void* const* d_in, const int* in_sizes, int n_in,
                              void* d_out, int out_size, void* d_ws, size_t ws_size,
                              hipStream_t stream) {
    const float* x     = (const float*)d_in[0];
    const float* coefs = (const float*)d_in[1];
    const float* cheb1 = (const float*)d_in[2];
    const float* cheb2 = (const float*)d_in[3];
    float* out = (float*)d_out;

    const size_t aux_bytes = 163840 + 163840 + 15360;          // cheb1T + cheb2T + coefTT
    size_t aux_off = (ws_size - aux_bytes) & ~(size_t)255;
    ushort16* cheb1T = (ushort16*)((char*)d_ws + aux_off);
    ushort16* cheb2T = cheb1T + 81920;
    ushort16* coefTT = cheb2T + 81920;
    ushort16* t1 = (ushort16*)d_ws;

    const size_t per_b = (size_t)NK * NC * LEN * LEN * sizeof(ushort16);   // 327680 B
    int chunk = (int)(aux_off / per_b);
    if (chunk < 1) chunk = 1;
    if (chunk > NB) chunk = NB;

    hipLaunchKernelGGL(k0_prep, dim3((171520 + 255) / 256), dim3(256), 0, stream,
                       coefs, cheb1, cheb2, cheb1T, cheb2T, coefTT);
    for (int b0 = 0; b0 < NB; b0 += chunk) {
        int cb = (NB - b0 < chunk) ? (NB - b0) : chunk;
        hipLaunchKernelGGL(k1_mfma, dim3(NC, cb), dim3(256), 0, stream,
                           x, (const uint32*)cheb1T, t1, b0);
        hipLaunchKernelGGL(k2_mfma, dim3(64, cb), dim3(256), 0, stream,
                           t1, coefTT, cheb2T, out, b0);
    }
}

// Round 2
// 150.973 us; speedup vs baseline: 1.1462x; 1.1441x over previous
//
#include <hip/hip_runtime.h>
#include <hip/hip_bf16.h>

#define LEN 128
#define NB 32
#define NC 16
#define NU 16
#define NK 5
#define KC 80          // (k,c) pairs
#define KCP 96         // padded K for stage2

typedef unsigned int uint32;
typedef unsigned short ushort16;
typedef __attribute__((ext_vector_type(8))) short bf16x8;
typedef __attribute__((ext_vector_type(4))) float f32x4;

#define MFMA(a, b, c) __builtin_amdgcn_mfma_f32_16x16x32_bf16(a, b, c, 0, 0, 0)

// XOR swizzle of the 16B-unit index within a 64-dword row (16 units).
#define SIG(r) (((r) & 15) ^ (((r) >> 3) & 15))

static __device__ inline ushort16 f2bf(float f) {
    union { float f; uint32 u; } v; v.f = f;
    uint32 u = v.u;
    uint32 r = (u + 0x7fffu + ((u >> 16) & 1u)) >> 16;   // RNE
    return (ushort16)r;
}
static __device__ inline uint32 pkbf(float a, float b) {   // low=a, high=b
    return (uint32)f2bf(a) | ((uint32)f2bf(b) << 16);
}
static __device__ inline bf16x8 frag16(const void* p) {    // 16B-aligned
    return *(const bf16x8*)p;
}

// ---------------- k0: constant operands -> MFMA fragment layout ----------------
// cheb1F[((nt*4+ks)*64+lane)*8+j]  = cheb1[k][h][p], kp=nt*16+(lane&15), h=ks*32+(lane>>4)*8+j   (nt 0..39)
// cheb2F[((nt*20+ks)*64+lane)*8+j] = cheb2[l][w][q], q=nt*16+(lane&15), lw=ks*32+(lane>>4)*8+j   (nt 0..7)
// coefF [((nt*3+ks)*64+lane)*8+j]  = coefs[k][l][c][u], lu=nt*16+(lane&15), kc=ks*32+(lane>>4)*8+j (zero for kc>=80)
__global__ __launch_bounds__(256) void k0_prep(const float* __restrict__ coefs,
                                               const float* __restrict__ cheb1,
                                               const float* __restrict__ cheb2,
                                               ushort16* __restrict__ cheb1F,
                                               ushort16* __restrict__ cheb2F,
                                               ushort16* __restrict__ coefF) {
    int i = blockIdx.x * 256 + threadIdx.x;
    if (i < 81920) {
        int j = i & 7, lane = (i >> 3) & 63, ks = (i >> 9) & 3, nt = i >> 11;
        int kp = nt * 16 + (lane & 15);
        int k = kp >> 7, p = kp & 127;
        int h = ks * 32 + ((lane >> 4) << 3) + j;
        cheb1F[i] = f2bf(cheb1[(k * LEN + h) * LEN + p]);
    } else if (i < 163840) {
        int i2 = i - 81920;
        int j = i2 & 7, lane = (i2 >> 3) & 63, t = i2 >> 9;
        int ks = t % 20, nt = t / 20;
        int q = nt * 16 + (lane & 15);
        int lw = ks * 32 + ((lane >> 4) << 3) + j;
        int l = lw >> 7, w = lw & 127;
        cheb2F[i2] = f2bf(cheb2[(l * LEN + w) * LEN + q]);
    } else if (i < 171520) {
        int i3 = i - 163840;
        int j = i3 & 7, lane = (i3 >> 3) & 63, t = i3 >> 9;
        int ks = t % 3, nt = t / 3;
        int lu = nt * 16 + (lane & 15);
        int l = lu >> 4, u = lu & 15;
        int kc = ks * 32 + ((lane >> 4) << 3) + j;
        int k = kc >> 4, c = kc & 15;
        coefF[i3] = (kc < KC) ? f2bf(coefs[((k * NK + l) * NC + c) * NU + u]) : (ushort16)0;
    }
}

// ---------------- kx: x -> xF fragment layout (A-operand of k1) ----------------
// xF[bc][((mt*4+ks)*64+lane)*8+j] = bf16(x[b][c][h][w]), w=mt*16+(lane&15), h=ks*32+(lane>>4)*8+j
__global__ __launch_bounds__(256) void kx_prep(const float* __restrict__ x,
                                               ushort16* __restrict__ xF) {
    __shared__ __align__(16) uint32 Xs[128 * 64];   // [w][h-pair units swizzled]
    const int bc = blockIdx.x;
    const int tid = threadIdx.x;
    const float* xp = x + (size_t)bc * (LEN * LEN);
    {
        int w = tid & 127, hg = tid >> 7;
        #pragma unroll
        for (int uu = 0; uu < 8; ++uu) {
            int u = hg * 8 + uu;
            uint4 d;
            uint32* dp = (uint32*)&d;
            #pragma unroll
            for (int t = 0; t < 4; ++t) {
                int h2 = u * 4 + t;
                dp[t] = pkbf(xp[(2 * h2) * LEN + w], xp[(2 * h2 + 1) * LEN + w]);
            }
            *(uint4*)(Xs + w * 64 + ((u ^ SIG(w)) << 2)) = d;
        }
    }
    __syncthreads();
    ushort16* dst = xF + (size_t)bc * 16384;
    #pragma unroll
    for (int i = 0; i < 8; ++i) {
        int n = tid + i * 256;               // 0..2047 fragment-units of 16B
        int lane = n & 63, fk = n >> 6;      // fk = mt*4+ks
        int wrow = (fk >> 2) * 16 + (lane & 15);
        int u = (fk & 3) * 4 + (lane >> 4);
        uint4 v = *(const uint4*)(Xs + wrow * 64 + ((u ^ SIG(wrow)) << 2));
        *(uint4*)(dst + (size_t)n * 8) = v;
    }
}

// ---------------- k1: t1[bl][p][kc][w] = sum_h cheb1[k][h][p]*x[b][c][h][w]
// grid (c, bl, nseg 0..7); nseg = 80 kp. LDS-free GEMM: both operands read as
// wave-contiguous 1KB fragments from global. Epilogue bounces through 20KB LDS
// so t1 stores are 256B-coalesced runs.
__global__ __launch_bounds__(256, 4) void k1_mfma(const ushort16* __restrict__ xF,
                                                  const ushort16* __restrict__ cheb1F,
                                                  ushort16* __restrict__ t1, int b0) {
    __shared__ __align__(16) uint32 Bs[80 * 64];   // bounce: 80 kp-rows x 128 w bf16, swizzled
    const int c = blockIdx.x, bl = blockIdx.y, ns = blockIdx.z;
    const int b = b0 + bl;
    const int tid = threadIdx.x;
    const int lane = tid & 63, wm = tid >> 6;      // wave = m-quarter
    const int m16 = lane & 15, g = lane >> 4;

    const ushort16* xFb = xF + ((size_t)(b * NC + c)) * 16384;

    f32x4 acc[2][5];
    #pragma unroll
    for (int mi = 0; mi < 2; ++mi)
        #pragma unroll
        for (int ni = 0; ni < 5; ++ni) acc[mi][ni] = (f32x4)0.f;

    #pragma unroll
    for (int ks = 0; ks < 4; ++ks) {
        bf16x8 Af[2], Bf[5];
        #pragma unroll
        for (int mi = 0; mi < 2; ++mi) {
            int mt = wm * 2 + mi;
            Af[mi] = frag16(xFb + ((size_t)(mt * 4 + ks) * 64 + lane) * 8);
        }
        #pragma unroll
        for (int ni = 0; ni < 5; ++ni) {
            int nt = ns * 5 + ni;
            Bf[ni] = frag16(cheb1F + ((size_t)(nt * 4 + ks) * 64 + lane) * 8);
        }
        #pragma unroll
        for (int mi = 0; mi < 2; ++mi)
            #pragma unroll
            for (int ni = 0; ni < 5; ++ni)
                acc[mi][ni] = MFMA(Af[mi], Bf[ni], acc[mi][ni]);
    }

    // bounce: D element (m = w = wm*32+mi*16+g*4+r, n = rr = ni*16+m16)
    #pragma unroll
    for (int ni = 0; ni < 5; ++ni)
        #pragma unroll
        for (int mi = 0; mi < 2; ++mi) {
            int rr = ni * 16 + m16;
            int wu = wm * 32 + mi * 16 + g * 4;       // ushort col (w)
            uint2 d;
            d.x = pkbf(acc[mi][ni][0], acc[mi][ni][1]);
            d.y = pkbf(acc[mi][ni][2], acc[mi][ni][3]);
            int u = wu >> 3;
            *(uint2*)(Bs + rr * 64 + ((u ^ SIG(rr)) << 2) + ((wu >> 1) & 3)) = d;
        }
    __syncthreads();

    // read-out + coalesced store (256B runs)
    #pragma unroll
    for (int i = 0; i < 5; ++i) {
        int n = tid + i * 256;                 // 0..1279
        int rr = n >> 4, wsg = n & 15;
        uint4 v = *(const uint4*)(Bs + rr * 64 + ((wsg ^ SIG(rr)) << 2));
        int kp = ns * 80 + rr;
        int k = kp >> 7, p = kp & 127;
        *(uint4*)(t1 + ((size_t)((bl * LEN + p) * KC + k * NC + c)) * LEN + wsg * 8) = v;
    }
}

// ---------------- k2: per (p, bl) block
// stage2: s[w(128)][lu(80)] = Ts[w][kc] x coefF, K=96 (zero-padded)
// stage3: out[u(16)][q(128)] = A3[u][lw] x cheb2F, K=640
__global__ __launch_bounds__(256, 4) void k2_mfma(const ushort16* __restrict__ t1,
                                                  const ushort16* __restrict__ coefF,
                                                  const ushort16* __restrict__ cheb2F,
                                                  float* __restrict__ out, int b0) {
    __shared__ __align__(16) uint32 sm[128 * 64];   // Ts [w][kc-pair units swz] 32KB; A3 aliases
    const int p = blockIdx.x, bl = blockIdx.y, b = b0 + bl;
    const int tid = threadIdx.x;
    const int lane = tid & 63, wave = tid >> 6;
    const int n16 = lane & 15, g = lane >> 4;

    // stage t1 slice [kc 80][w 128] -> Ts[w][kc-pairs], transpose + swizzle
    {
        const uint32* t1u = (const uint32*)(t1 + (size_t)(bl * LEN + p) * (KC * LEN));
        #pragma unroll
        for (int i = 0; i < 3; ++i) {
            int it = tid + i * 256;              // 0..639 active
            if (it < 640) {
                int a = it >> 4, wq = it & 15;   // a = kc-pair 0..39
                const uint32* src = t1u + (2 * a) * 64 + wq * 4;
                uint4 Av = *(const uint4*)(src);
                uint4 Bv = *(const uint4*)(src + 64);
                const uint32* av = (const uint32*)&Av;
                const uint32* bv = (const uint32*)&Bv;
                int u = a >> 2, lo = a & 3;
                #pragma unroll
                for (int j = 0; j < 4; ++j) {
                    int r0 = wq * 8 + 2 * j, r1 = r0 + 1;
                    sm[r0 * 64 + ((u ^ SIG(r0)) << 2) + lo] = (av[j] & 0xffffu) | (bv[j] << 16);
                    sm[r1 * 64 + ((u ^ SIG(r1)) << 2) + lo] = (av[j] >> 16) | (bv[j] & 0xffff0000u);
                }
            }
        }
        #pragma unroll
        for (int i = 0; i < 4; ++i) {           // zero K-pad (dw 40..47 = units 10,11)
            int idx = tid + i * 256;             // 0..1023
            int row = idx >> 3, d = idx & 7;
            int u = 10 + (d >> 2);
            sm[row * 64 + ((u ^ SIG(row)) << 2) + (d & 3)] = 0;
        }
    }
    __syncthreads();

    // ---- stage2: rows w = wave*32 + mi*16 + n16
    f32x4 acc[2][5];
    #pragma unroll
    for (int mi = 0; mi < 2; ++mi)
        #pragma unroll
        for (int ni = 0; ni < 5; ++ni) acc[mi][ni] = (f32x4)0.f;

    #pragma unroll
    for (int ks = 0; ks < 3; ++ks) {
        bf16x8 Af[2], Bf[5];
        #pragma unroll
        for (int mi = 0; mi < 2; ++mi) {
            int row = wave * 32 + mi * 16 + n16;
            int uu = ks * 4 + g;
            Af[mi] = frag16(sm + row * 64 + ((uu ^ SIG(row)) << 2));
        }
        #pragma unroll
        for (int ni = 0; ni < 5; ++ni)
            Bf[ni] = frag16(coefF + ((size_t)(ni * 3 + ks) * 64 + lane) * 8);
        #pragma unroll
        for (int mi = 0; mi < 2; ++mi)
            #pragma unroll
            for (int ni = 0; ni < 5; ++ni)
                acc[mi][ni] = MFMA(Af[mi], Bf[ni], acc[mi][ni]);
    }
    __syncthreads();   // Ts reads done; A3 may overwrite

    // s -> A3: row u = n16 (16 rows, stride 648 ushort), col l*128+w
    {
        ushort16* A3 = (ushort16*)sm;
        #pragma unroll
        for (int mi = 0; mi < 2; ++mi)
            #pragma unroll
            for (int ni = 0; ni < 5; ++ni) {
                int wcol = wave * 32 + mi * 16 + g * 4;
                uint2 d;
                d.x = pkbf(acc[mi][ni][0], acc[mi][ni][1]);
                d.y = pkbf(acc[mi][ni][2], acc[mi][ni][3]);
                *(uint2*)(A3 + n16 * 648 + ni * 128 + wcol) = d;
            }
    }
    __syncthreads();

    // ---- stage3: M=16 (u), wave owns 32 q
    const ushort16* A3r = (const ushort16*)sm;
    f32x4 c3[2];
    c3[0] = (f32x4)0.f; c3[1] = (f32x4)0.f;
    #pragma unroll 5
    for (int ks = 0; ks < 20; ++ks) {
        bf16x8 Aa = frag16(A3r + n16 * 648 + ks * 32 + g * 8);
        #pragma unroll
        for (int nt = 0; nt < 2; ++nt) {
            bf16x8 Bb = frag16(cheb2F + ((size_t)((wave * 2 + nt) * 20 + ks) * 64 + lane) * 8);
            c3[nt] = MFMA(Aa, Bb, c3[nt]);
        }
    }

    #pragma unroll
    for (int nt = 0; nt < 2; ++nt)
        #pragma unroll
        for (int r = 0; r < 4; ++r) {
            int u = g * 4 + r;
            int q = wave * 32 + nt * 16 + n16;
            out[(((size_t)(b * NU + u)) * LEN + p) * LEN + q] = c3[nt][r];
        }
}

extern "C" void kernel_launch(void* const* d_in, const int* in_sizes, int n_in,
                              void* d_out, int out_size, void* d_ws, size_t ws_size,
                              hipStream_t stream) {
    const float* x     = (const float*)d_in[0];
    const float* coefs = (const float*)d_in[1];
    const float* cheb1 = (const float*)d_in[2];
    const float* cheb2 = (const float*)d_in[3];
    float* out = (float*)d_out;

    const size_t xF_bytes  = (size_t)NB * NC * 16384 * sizeof(ushort16);   // 16.8 MB
    const size_t aux_bytes = 163840 + 163840 + 15360;                      // cheb1F + cheb2F + coefF
    size_t off = (ws_size - aux_bytes - xF_bytes) & ~(size_t)255;
    ushort16* cheb1F = (ushort16*)((char*)d_ws + off);
    ushort16* cheb2F = cheb1F + 81920;
    ushort16* coefF  = cheb2F + 81920;
    ushort16* xF     = coefF + 7680;
    ushort16* t1 = (ushort16*)d_ws;

    const size_t per_b = (size_t)LEN * KC * LEN * sizeof(ushort16);        // 2.62 MB
    int chunk = (int)(off / per_b);
    if (chunk < 1) chunk = 1;
    if (chunk > NB) chunk = NB;

    hipLaunchKernelGGL(k0_prep, dim3(171520 / 256), dim3(256), 0, stream,
                       coefs, cheb1, cheb2, cheb1F, cheb2F, coefF);
    hipLaunchKernelGGL(kx_prep, dim3(NB * NC), dim3(256), 0, stream, x, xF);
    for (int b0 = 0; b0 < NB; b0 += chunk) {
        int cb = (NB - b0 < chunk) ? (NB - b0) : chunk;
        hipLaunchKernelGGL(k1_mfma, dim3(NC, cb, 8), dim3(256), 0, stream,
                           xF, cheb1F, t1, b0);
        hipLaunchKernelGGL(k2_mfma, dim3(LEN, cb), dim3(256), 0, stream,
                           t1, coefF, cheb2F, out, b0);
    }
}